// Round 1
// baseline (41.750 us; speedup 1.0000x reference)
//
#include <hip/hip_runtime.h>

// PercentageEliminationLoss: B=128, N=4096, K=256
//   loss = sum_{b,k,n} [valid(k) & surv(n)] * relu(s_e[b,k] - s[b,n] + m)
//   pairs = sum_b E_b * S_b ; out = loss / max(pairs,1)
//
// ws layout:
//   [0]  int mtype   (0=int32, 1=uint8, 2=float32)  -- mask wire format
//   [4]  int itype   (0=int32, 1=int64)             -- idx wire format
//   [64] double partial_loss[512]
//   [64+4096] unsigned long long partial_pairs[512]

#define BB 128
#define NN 4096
#define KK 256
#define SPLIT 4
#define NCHUNK (NN / SPLIT)   // 1024
#define NBLK (BB * SPLIT)     // 512
#define MARGIN_F 0.01f

__global__ void pel_detect(const unsigned int* __restrict__ mask_w,
                           const unsigned int* __restrict__ idx_w,
                           int* __restrict__ flags) {
  if (threadIdx.x == 0 && blockIdx.x == 0) {
    // mask dtype sniff: float32 1.0 -> 0x3F800000; uint8-packed words can be
    // >1 (e.g. 0x0101); pure int32 0/1 words stay <=1.
    int mtype = 0;
    for (int i = 0; i < 256; ++i) {
      unsigned int w = mask_w[i];
      if (w == 0x3F800000u) { mtype = 2; break; }
      if (w > 1u) { mtype = 1; break; }
    }
    // idx dtype sniff: int64 (values < 4096, >=0) -> every odd 32-bit word is
    // the zero high-half. True int32 data has random values at odd positions.
    int itype = 1;
    for (int j = 0; j < 64; ++j) {
      if (idx_w[2 * j + 1] != 0u) { itype = 0; break; }
    }
    flags[0] = mtype;
    flags[1] = itype;
  }
}

__device__ __forceinline__ bool read_mask(const void* mask_v, int mtype, size_t i) {
  if (mtype == 1) return ((const unsigned char*)mask_v)[i] != 0;
  if (mtype == 2) return ((const float*)mask_v)[i] != 0.0f;
  return ((const int*)mask_v)[i] != 0;
}

__global__ __launch_bounds__(256) void pel_main(
    const float* __restrict__ scores,
    const void* __restrict__ idx_v,
    const void* __restrict__ mask_v,
    const int* __restrict__ flags,
    double* __restrict__ partial_loss,
    unsigned long long* __restrict__ partial_pairs) {
  const int blk = blockIdx.x;
  const int b = blk >> 2;          // SPLIT = 4
  const int part = blk & 3;
  const int tid = threadIdx.x;
  const int mtype = flags[0];
  const int itype = flags[1];

  __shared__ __align__(16) float svals[NCHUNK];  // surv ? score : +1e30
  __shared__ unsigned char elimf[NCHUNK];
  __shared__ double sd[256];
  __shared__ int se[256];
  __shared__ int ss[256];

  const int n0 = part * NCHUNK;
  const size_t row = (size_t)b * NN;

  // Each thread owns one eliminated slot k = tid (K == blockDim).
  int ki;
  if (itype == 1) ki = (int)((const long long*)idx_v)[(size_t)b * KK + tid];
  else            ki = ((const int*)idx_v)[(size_t)b * KK + tid];

  const bool kvalid = read_mask(mask_v, mtype, row + ki);

  // Mark eliminated positions within this block's n-range.
  for (int i = tid; i < NCHUNK; i += 256) elimf[i] = 0;
  __syncthreads();
  if (ki >= n0 && ki < n0 + NCHUNK) elimf[ki - n0] = 1;  // same-value races benign
  __syncthreads();

  // Build masked survivor scores; count survivors in this range.
  int my_s = 0;
  for (int i = tid; i < NCHUNK; i += 256) {
    const int n = n0 + i;
    const bool mv = read_mask(mask_v, mtype, row + n);
    const bool surv = mv && (elimf[i] == 0);
    const float s = scores[row + n];
    svals[i] = surv ? s : 1e30f;   // relu(e' - 1e30) == 0, branch-free mask
    my_s += surv ? 1 : 0;
  }
  __syncthreads();

  const float eprime = kvalid ? (scores[row + ki] + MARGIN_F) : -1e30f;

  // Inner pair loop: 1024 LDS-broadcast terms, 3 VALU each; flush to double
  // every 256 terms to bound the fp32 accumulation chain.
  double dacc = 0.0;
  for (int j0 = 0; j0 < NCHUNK; j0 += 256) {
    float facc = 0.0f;
#pragma unroll
    for (int j = 0; j < 256; j += 4) {
      const float4 s4 = *reinterpret_cast<const float4*>(&svals[j0 + j]);
      facc += fmaxf(eprime - s4.x, 0.0f);
      facc += fmaxf(eprime - s4.y, 0.0f);
      facc += fmaxf(eprime - s4.z, 0.0f);
      facc += fmaxf(eprime - s4.w, 0.0f);
    }
    dacc += (double)facc;
  }

  // Deterministic block tree-reduction in LDS.
  sd[tid] = dacc;
  se[tid] = kvalid ? 1 : 0;
  ss[tid] = my_s;
  __syncthreads();
  for (int s = 128; s > 0; s >>= 1) {
    if (tid < s) {
      sd[tid] += sd[tid + s];
      se[tid] += se[tid + s];
      ss[tid] += ss[tid + s];
    }
    __syncthreads();
  }
  if (tid == 0) {
    partial_loss[blk] = sd[0];
    partial_pairs[blk] = (unsigned long long)se[0] * (unsigned long long)ss[0];
  }
}

__global__ __launch_bounds__(256) void pel_final(
    const double* __restrict__ partial_loss,
    const unsigned long long* __restrict__ partial_pairs,
    float* __restrict__ out) {
  __shared__ double sd[256];
  __shared__ unsigned long long sp[256];
  const int tid = threadIdx.x;
  sd[tid] = partial_loss[tid] + partial_loss[tid + 256];
  sp[tid] = partial_pairs[tid] + partial_pairs[tid + 256];
  __syncthreads();
  for (int s = 128; s > 0; s >>= 1) {
    if (tid < s) { sd[tid] += sd[tid + s]; sp[tid] += sp[tid + s]; }
    __syncthreads();
  }
  if (tid == 0) {
    const unsigned long long pt = sp[0];
    const double denom = (pt == 0ull) ? 1.0 : (double)pt;
    out[0] = (float)(sd[0] / denom);
  }
}

extern "C" void kernel_launch(void* const* d_in, const int* in_sizes, int n_in,
                              void* d_out, int out_size, void* d_ws, size_t ws_size,
                              hipStream_t stream) {
  const float* scores = (const float*)d_in[0];
  const void* idx = d_in[1];
  const void* mask = d_in[2];

  char* ws = (char*)d_ws;
  int* flags = (int*)ws;
  double* ploss = (double*)(ws + 64);
  unsigned long long* ppairs = (unsigned long long*)(ws + 64 + NBLK * sizeof(double));
  float* out = (float*)d_out;

  pel_detect<<<1, 64, 0, stream>>>((const unsigned int*)mask, (const unsigned int*)idx, flags);
  pel_main<<<NBLK, 256, 0, stream>>>(scores, idx, mask, flags, ploss, ppairs);
  pel_final<<<1, 256, 0, stream>>>(ploss, ppairs, out);
}

// Round 2
// 20.762 us; speedup vs baseline: 2.0109x; 2.0109x over previous
//
#include <hip/hip_runtime.h>

// PercentageEliminationLoss: B=128, N=4096, K=256
//   loss  = sum_{b,k,n} [valid(k) & surv(n)] * relu(s_e[b,k] - s[b,n] + m)
//   pairs = sum_b E_b * S_b ; out = loss / max(pairs,1)
//
// Fused 2-dispatch version: dtype detection inlined per-block (parallel,
// wave-0 ballot over the first 256B of mask / first 64 idx high-words).
//
// ws layout:
//   [0]                 double partial_loss[1024]
//   [1024*8]            unsigned int partial_pairs[1024]

#define BB 128
#define NN 4096
#define KK 256
#define SPLIT 8
#define NCHUNK (NN / SPLIT)   // 512
#define NBLK (BB * SPLIT)     // 1024
#define MARGIN_F 0.01f

__device__ __forceinline__ bool read_mask1(const void* mask_v, int mtype, size_t i) {
  if (mtype == 1) return ((const unsigned char*)mask_v)[i] != 0;
  if (mtype == 2) return ((const float*)mask_v)[i] != 0.0f;
  return ((const int*)mask_v)[i] != 0;
}

__global__ __launch_bounds__(256) void pel_main(
    const float* __restrict__ scores,
    const void* __restrict__ idx_v,
    const void* __restrict__ mask_v,
    double* __restrict__ partial_loss,
    unsigned int* __restrict__ partial_pairs) {
  const int blk = blockIdx.x;
  const int b = blk >> 3;          // SPLIT = 8
  const int part = blk & 7;
  const int tid = threadIdx.x;
  const int lane = tid & 63;
  const int wid = tid >> 6;

  __shared__ __align__(16) float svals[NCHUNK];  // surv ? score : +1e30
  __shared__ unsigned char elimf[NCHUNK];
  __shared__ int flagsh[2];
  __shared__ double sdw[4];
  __shared__ unsigned int scw[4];

  // --- inline dtype detection: wave 0, two ballots, ~0.3us, L2-broadcast ---
  // mask: float32 1.0 word = 0x3F800000; uint8-packed words exceed 1 with
  // certainty over 256 bytes at p=0.7; int32 0/1 words never do.
  // idx: int64 values <4096 have all-zero odd (high) words; int32 wire data
  // has random nonzero values there.
  if (wid == 0) {
    const unsigned int mw = ((const unsigned int*)mask_v)[lane];
    const unsigned long long isF = __ballot(mw == 0x3F800000u);
    const unsigned long long gt1 = __ballot(mw > 1u);
    const unsigned int hw = ((const unsigned int*)idx_v)[2 * lane + 1];
    const unsigned long long hi = __ballot(hw != 0u);
    if (lane == 0) {
      flagsh[0] = isF ? 2 : (gt1 ? 1 : 0);
      flagsh[1] = hi ? 0 : 1;
    }
  }
  if (tid < NCHUNK / 4) ((unsigned int*)elimf)[tid] = 0u;
  __syncthreads();

  const int mtype = flagsh[0];
  const int itype = flagsh[1];
  const int n0 = part * NCHUNK;
  const size_t row = (size_t)b * NN;

  // Each thread owns one eliminated slot k = tid (K == blockDim).
  int ki;
  if (itype) ki = (int)((const long long*)idx_v)[(size_t)b * KK + tid];
  else       ki = ((const int*)idx_v)[(size_t)b * KK + tid];
  const bool kvalid = read_mask1(mask_v, mtype, row + (size_t)ki);
  if (ki >= n0 && ki < n0 + NCHUNK) elimf[ki - n0] = 1;  // same-value races benign
  __syncthreads();

  // Staging: 2 consecutive survivor slots per thread, vectorized loads.
  int my_s = 0;
  {
    const int i0 = tid * 2;
    const size_t n = row + (size_t)(n0 + i0);
    const float2 s2 = *reinterpret_cast<const float2*>(&scores[n]);
    bool m0, m1;
    if (mtype == 1) {
      const unsigned short w = ((const unsigned short*)mask_v)[n >> 1];
      m0 = (w & 0xffu) != 0; m1 = (w >> 8) != 0;
    } else if (mtype == 2) {
      const float2 w = *reinterpret_cast<const float2*>(&((const float*)mask_v)[n]);
      m0 = (w.x != 0.0f); m1 = (w.y != 0.0f);
    } else {
      const int2 w = *reinterpret_cast<const int2*>(&((const int*)mask_v)[n]);
      m0 = (w.x != 0); m1 = (w.y != 0);
    }
    const bool surv0 = m0 && (elimf[i0] == 0);
    const bool surv1 = m1 && (elimf[i0 + 1] == 0);
    float2 o2;
    o2.x = surv0 ? s2.x : 1e30f;   // relu(ep - 1e30) == 0: branch-free mask
    o2.y = surv1 ? s2.y : 1e30f;
    *reinterpret_cast<float2*>(&svals[i0]) = o2;
    my_s = (surv0 ? 1 : 0) + (surv1 ? 1 : 0);
  }
  __syncthreads();

  const float ep = kvalid ? (scores[row + (size_t)ki] + MARGIN_F) : -1e30f;

  // Inner pair loop: 512 LDS-broadcast terms, 3 VALU each; 4 independent
  // accumulators break the fp32 add dependency chain.
  float f0 = 0.0f, f1 = 0.0f, f2 = 0.0f, f3 = 0.0f;
#pragma unroll 16
  for (int j = 0; j < NCHUNK; j += 4) {
    const float4 v = *reinterpret_cast<const float4*>(&svals[j]);
    f0 += fmaxf(ep - v.x, 0.0f);
    f1 += fmaxf(ep - v.y, 0.0f);
    f2 += fmaxf(ep - v.z, 0.0f);
    f3 += fmaxf(ep - v.w, 0.0f);
  }
  double dacc = (double)((f0 + f1) + (f2 + f3));

  // Packed count: (kvalid << 16) | survivors. Block sums stay < 2^16 per
  // field (kv <= 256, surv <= 512) -> no cross-field carry.
  unsigned int cnt = ((kvalid ? 1u : 0u) << 16) | (unsigned int)my_s;

  // Wave shuffle reduction (no LDS tree, no per-step syncs).
  for (int off = 32; off > 0; off >>= 1) {
    dacc += __shfl_down(dacc, off);
    cnt  += __shfl_down(cnt, off);
  }
  if (lane == 0) { sdw[wid] = dacc; scw[wid] = cnt; }
  __syncthreads();
  if (tid == 0) {
    const double d = (sdw[0] + sdw[1]) + (sdw[2] + sdw[3]);
    const unsigned int c = scw[0] + scw[1] + scw[2] + scw[3];
    partial_loss[blk] = d;
    partial_pairs[blk] = (c >> 16) * (c & 0xffffu);  // E_b * S_{b,part}
  }
}

__global__ __launch_bounds__(256) void pel_final(
    const double* __restrict__ partial_loss,
    const unsigned int* __restrict__ partial_pairs,
    float* __restrict__ out) {
  const int tid = threadIdx.x;
  const int lane = tid & 63;
  const int wid = tid >> 6;
  __shared__ double sdw[4];
  __shared__ unsigned long long spw[4];

  double d = (partial_loss[tid] + partial_loss[tid + 256]) +
             (partial_loss[tid + 512] + partial_loss[tid + 768]);
  unsigned long long p =
      (unsigned long long)partial_pairs[tid] + partial_pairs[tid + 256] +
      partial_pairs[tid + 512] + partial_pairs[tid + 768];
  for (int off = 32; off > 0; off >>= 1) {
    d += __shfl_down(d, off);
    p += __shfl_down(p, off);
  }
  if (lane == 0) { sdw[wid] = d; spw[wid] = p; }
  __syncthreads();
  if (tid == 0) {
    const double dt = (sdw[0] + sdw[1]) + (sdw[2] + sdw[3]);
    const unsigned long long pt = spw[0] + spw[1] + spw[2] + spw[3];
    out[0] = (float)(dt / (pt ? (double)pt : 1.0));
  }
}

extern "C" void kernel_launch(void* const* d_in, const int* in_sizes, int n_in,
                              void* d_out, int out_size, void* d_ws, size_t ws_size,
                              hipStream_t stream) {
  const float* scores = (const float*)d_in[0];
  const void* idx = d_in[1];
  const void* mask = d_in[2];

  char* ws = (char*)d_ws;
  double* ploss = (double*)ws;
  unsigned int* ppairs = (unsigned int*)(ws + NBLK * sizeof(double));
  float* out = (float*)d_out;

  pel_main<<<NBLK, 256, 0, stream>>>(scores, idx, mask, ploss, ppairs);
  pel_final<<<1, 256, 0, stream>>>(ploss, ppairs, out);
}

// Round 3
// 17.672 us; speedup vs baseline: 2.3625x; 1.1748x over previous
//
#include <hip/hip_runtime.h>

// PercentageEliminationLoss via bucketed suffix-sums, single fused dispatch.
//   loss = sum_{b,k,n} [valid(k) & surv(n)] * relu(e'_k - s_n),  e' = s_elim + m
//   For survivor s with bucket q: contribution = sfx_sum[q] - sfx_cnt[q]*s
//     + sum over own-bucket e' of max(e'-s,0).   (exact for any monotone qb)
//   pairs = sum_b E_b * S_b ; out = loss / max(pairs,1)
//
// Determinism: integer (fixed-point 2^38) LDS atomics only; float reductions
// in fixed order. Last-block finalize via monotonic counter (poison-proof).
//
// ws: [0] u32 counter | [64] double ploss[256] | [64+2048] u32 ppairs[256]

#define BB 128
#define NN 4096
#define KK 256
#define NBLK 256          // 2 blocks per batch
#define BT 512
#define HALF 2048         // survivor slots per block
#define NBUCK 1024
#define MARGIN_F 0.01f
#define FIX_SCALE 274877906944.0   // 2^38
#define FIX_INV (1.0 / 274877906944.0)

__device__ __forceinline__ int qbucket(float x) {
  int t = (int)((x + 8.0f) * 64.0f);   // monotone (fp add/mul/trunc monotone)
  t = t < 0 ? 0 : t;
  return t > 1023 ? 1023 : t;
}
__device__ __forceinline__ long long fixv(float x) {
  return (long long)((double)x * FIX_SCALE);   // exact mantissa, trunc 2^-38
}
__device__ __forceinline__ bool rmask(const void* mv, int mtype, size_t i) {
  if (mtype == 1) return ((const unsigned char*)mv)[i] != 0;
  if (mtype == 2) return ((const float*)mv)[i] != 0.0f;
  return ((const int*)mv)[i] != 0;
}

__global__ __launch_bounds__(BT) void pel_fused(
    const float* __restrict__ scores,
    const void* __restrict__ idx_v,
    const void* __restrict__ mask_v,
    double* __restrict__ ploss,
    unsigned int* __restrict__ ppairs,
    unsigned int* __restrict__ counter,
    float* __restrict__ out) {
  const int blk = blockIdx.x;
  const int b = blk >> 1;
  const int n0 = (blk & 1) * HALF;
  const int tid = threadIdx.x;
  const int lane = tid & 63;
  const int wid = tid >> 6;
  const size_t row = (size_t)b * NN;

  __shared__ int cnt[NBUCK];
  __shared__ int qoff[NBUCK];
  __shared__ unsigned long long fsum[NBUCK];
  __shared__ int sfx_c[NBUCK];
  __shared__ long long sfx_f[NBUCK];
  __shared__ int qst[NBUCK];
  __shared__ float sq[KK];
  __shared__ unsigned char elimf[HALF];
  __shared__ int flagsh[2];
  __shared__ int wtc[8];
  __shared__ long long wtf[8];
  __shared__ double rd[8];
  __shared__ long long rf[8];
  __shared__ int rs[8];
  __shared__ unsigned long long rp[8];
  __shared__ int Etot_s;
  __shared__ int lastflag;

  // Prefetch survivor scores early (address independent of dtype detection).
  const int i0 = tid * 4;
  const float4 s4 = *reinterpret_cast<const float4*>(&scores[row + n0 + i0]);

  // Inline dtype detection (wave 0): mask wire format + idx width.
  if (wid == 0) {
    const unsigned int mw = ((const unsigned int*)mask_v)[lane];
    const unsigned long long isF = __ballot(mw == 0x3F800000u);
    const unsigned long long gt1 = __ballot(mw > 1u);
    const unsigned int hw = ((const unsigned int*)idx_v)[2 * lane + 1];
    const unsigned long long hi = __ballot(hw != 0u);
    if (lane == 0) {
      flagsh[0] = isF ? 2 : (gt1 ? 1 : 0);  // 0=int32 1=uint8 2=float32
      flagsh[1] = hi ? 0 : 1;               // 0=int32 1=int64
    }
  }
  cnt[tid] = 0;  cnt[tid + BT] = 0;
  qoff[tid] = 0; qoff[tid + BT] = 0;
  fsum[tid] = 0ull; fsum[tid + BT] = 0ull;
  ((unsigned int*)elimf)[tid] = 0u;
  __syncthreads();  // S1

  const int mtype = flagsh[0];
  const int itype = flagsh[1];

  // Query phase (tid<256): histogram valid e' into fixed-point bucket sums.
  int ki = 0; bool kvalid = false; float ep = 0.0f; int qb = 0;
  if (tid < KK) {
    if (itype) ki = (int)((const long long*)idx_v)[(size_t)b * KK + tid];
    else       ki = ((const int*)idx_v)[(size_t)b * KK + tid];
    kvalid = rmask(mask_v, mtype, row + (size_t)ki);
    ep = scores[row + (size_t)ki] + MARGIN_F;
    if (ki >= n0 && ki < n0 + HALF) elimf[ki - n0] = 1;  // same-value race ok
    if (kvalid) {
      qb = qbucket(ep);
      atomicAdd(&cnt[qb], 1);
      atomicAdd(&fsum[qb], (unsigned long long)fixv(ep));  // exact, order-free
    }
  }
  // Survivor mask loads (dtype known now).
  bool m0, m1, m2, m3;
  {
    const size_t n = row + (size_t)(n0 + i0);
    if (mtype == 1) {
      const unsigned int w =
          *reinterpret_cast<const unsigned int*>((const unsigned char*)mask_v + n);
      m0 = (w & 0xffu) != 0;     m1 = (w & 0xff00u) != 0;
      m2 = (w & 0xff0000u) != 0; m3 = (w & 0xff000000u) != 0;
    } else if (mtype == 2) {
      const float4 w = *reinterpret_cast<const float4*>(&((const float*)mask_v)[n]);
      m0 = w.x != 0.0f; m1 = w.y != 0.0f; m2 = w.z != 0.0f; m3 = w.w != 0.0f;
    } else {
      const int4 w = *reinterpret_cast<const int4*>(&((const int*)mask_v)[n]);
      m0 = w.x != 0; m1 = w.y != 0; m2 = w.z != 0; m3 = w.w != 0;
    }
  }
  __syncthreads();  // S2

  // Suffix scans over 1024 buckets (2 per thread): counts + fixed-point sums.
  const int b0 = tid * 2;
  const int c0 = cnt[b0], c1 = cnt[b0 + 1];
  const long long f0 = (long long)fsum[b0], f1 = (long long)fsum[b0 + 1];
  const int pc = c0 + c1;
  const long long pf = f0 + f1;
  int ic = pc; long long ifx = pf;
  for (int off = 1; off < 64; off <<= 1) {   // guarded inclusive suffix scan
    const int tc = __shfl_down(ic, off);
    const long long tf = __shfl_down(ifx, off);
    if (lane + off < 64) { ic += tc; ifx += tf; }
  }
  if (lane == 0) { wtc[wid] = ic; wtf[wid] = ifx; }
  __syncthreads();  // S3
  int wc = 0; long long wf = 0;
  for (int w = wid + 1; w < 8; ++w) { wc += wtc[w]; wf += wtf[w]; }
  const int Ac = ic - pc + wc;          // exclusive-above my bucket pair
  const long long Af = ifx - pf + wf;
  sfx_c[b0 + 1] = Ac;      sfx_f[b0 + 1] = Af;
  sfx_c[b0] = Ac + c1;     sfx_f[b0] = Af + f1;
  if (tid == 0) Etot_s = ic + wc;       // total valid queries E_b
  __syncthreads();  // S4
  const int E = Etot_s;
  qst[b0] = E - sfx_c[b0] - c0;         // prefix-below = scatter base
  qst[b0 + 1] = E - sfx_c[b0 + 1] - c1;
  __syncthreads();  // S5

  // Scatter valid e' grouped by bucket (slot order nondet -> harmless:
  // own-bucket accumulation is order-free fixed-point).
  if (tid < KK && kvalid) {
    const int pos = qst[qb] + atomicAdd(&qoff[qb], 1);
    sq[pos] = ep;
  }
  __syncthreads();  // S6

  // Survivor phase: 4 per thread.
  long long afix = 0; double cs = 0.0; int ns = 0;
  {
    const float sv[4] = {s4.x, s4.y, s4.z, s4.w};
    const bool mm[4] = {m0, m1, m2, m3};
#pragma unroll
    for (int e = 0; e < 4; ++e) {
      if (mm[e] && (elimf[i0 + e] == 0)) {
        const float s = sv[e];
        ++ns;
        const int q = qbucket(s);
        cs += (double)sfx_c[q] * (double)s;
        afix += sfx_f[q];
        const int st = qst[q];
        const int c = cnt[q];
        for (int j = 0; j < c; ++j) {     // own-bucket exact scan (~0-3 elems)
          const float t = sq[st + j] - s;
          if (t > 0.0f) afix += fixv(t);
        }
      }
    }
  }

  // Block reduce (descending shuffle, lane0-valid) in fixed order.
  for (int off = 32; off > 0; off >>= 1) {
    afix += __shfl_down(afix, off);
    cs += __shfl_down(cs, off);
    ns += __shfl_down(ns, off);
  }
  if (lane == 0) { rf[wid] = afix; rd[wid] = cs; rs[wid] = ns; }
  __syncthreads();  // S7
  if (tid == 0) {
    long long F = 0; double C = 0.0; int S = 0;
    for (int w = 0; w < 8; ++w) { F += rf[w]; C += rd[w]; S += rs[w]; }
    ploss[blk] = (double)F * FIX_INV - C;
    ppairs[blk] = (unsigned int)(E * S);
    __threadfence();
    const unsigned int old = atomicAdd(counter, 1u);
    lastflag = ((old & (NBLK - 1)) == (NBLK - 1)) ? 1 : 0;  // poison-proof
  }
  __syncthreads();  // S8

  if (lastflag) {   // exactly one block per call; all partials fenced+visible
    __threadfence();
    double d = 0.0; unsigned long long p = 0ull;
    if (tid < NBLK) {
      d = __hip_atomic_load(&ploss[tid], __ATOMIC_RELAXED, __HIP_MEMORY_SCOPE_AGENT);
      p = (unsigned long long)__hip_atomic_load(&ppairs[tid], __ATOMIC_RELAXED,
                                                __HIP_MEMORY_SCOPE_AGENT);
    }
    for (int off = 32; off > 0; off >>= 1) {
      d += __shfl_down(d, off);
      p += __shfl_down(p, off);
    }
    if (lane == 0) { rd[wid] = d; rp[wid] = p; }
    __syncthreads();
    if (tid == 0) {
      double D = 0.0; unsigned long long P = 0ull;
      for (int w = 0; w < 8; ++w) { D += rd[w]; P += rp[w]; }
      out[0] = (float)(D / (P ? (double)P : 1.0));
    }
  }
}

extern "C" void kernel_launch(void* const* d_in, const int* in_sizes, int n_in,
                              void* d_out, int out_size, void* d_ws, size_t ws_size,
                              hipStream_t stream) {
  const float* scores = (const float*)d_in[0];
  const void* idx = d_in[1];
  const void* mask = d_in[2];

  char* ws = (char*)d_ws;
  unsigned int* counter = (unsigned int*)ws;
  double* ploss = (double*)(ws + 64);
  unsigned int* ppairs = (unsigned int*)(ws + 64 + NBLK * sizeof(double));
  float* out = (float*)d_out;

  pel_fused<<<NBLK, BT, 0, stream>>>(scores, idx, mask, ploss, ppairs, counter, out);
}

// Round 4
// 17.295 us; speedup vs baseline: 2.4140x; 1.0218x over previous
//
#include <hip/hip_runtime.h>

// PercentageEliminationLoss via bucketed suffix-sums, single fused dispatch.
//   loss = sum_{b,k,n} [valid(k) & surv(n)] * relu(e'_k - s_n),  e' = s_elim + m
//   survivor s in bucket q: contribution = sfx_f[q] - sfx_c[q]*s
//     + sum over own-bucket e' of max(e'-s,0)   (exact for monotone buckets:
//     qb(e') > qb(s) implies e' > s)
//   pairs = sum_b E_b * S_b ; out = loss / max(pairs,1)
//
// Determinism: LDS atomics only on integers / 2^-38 fixed-point (order-free
// exact); float reductions in fixed tree order. Last-block finalize via
// monotonic counter ((old & 255)==255 fires once per call for any poison).
//
// ws: [0] u32 counter | [64] double ploss[256] | [64+2048] u32 ppairs[256]

#define NN 4096
#define KK 256
#define NBLK 256          // 2 blocks per batch
#define BT 512
#define HALF 2048         // survivor slots per block
#define NBUCK 1024
#define MARGIN_F 0.01f
#define FIX_SCALE 274877906944.0   // 2^38
#define FIX_INV (1.0 / 274877906944.0)

__device__ __forceinline__ int qbucket(float x) {
  int t = (int)((x + 8.0f) * 64.0f);   // monotone (fp add/mul/trunc monotone)
  t = t < 0 ? 0 : t;
  return t > 1023 ? 1023 : t;
}
__device__ __forceinline__ long long fixv(float x) {
  return (long long)((double)x * FIX_SCALE);   // exact mantissa, trunc 2^-38
}
__device__ __forceinline__ bool rmask(const void* mv, int mtype, size_t i) {
  if (mtype == 1) return ((const unsigned char*)mv)[i] != 0;
  if (mtype == 2) return ((const float*)mv)[i] != 0.0f;
  return ((const int*)mv)[i] != 0;
}

struct __align__(16) Bucket {
  long long sfx_f;       // fixed-point sum of e' in buckets strictly above
  unsigned int packed;   // cnt<<20 | qst<<10 | sfx_c   (each field <= 256)
  unsigned int pad;
};

__global__ __launch_bounds__(BT) void pel_fused(
    const float* __restrict__ scores,
    const void* __restrict__ idx_v,
    const void* __restrict__ mask_v,
    double* __restrict__ ploss,
    unsigned int* __restrict__ ppairs,
    unsigned int* __restrict__ counter,
    float* __restrict__ out) {
  const int blk = blockIdx.x;
  const int b = blk >> 1;
  const int n0 = (blk & 1) * HALF;
  const int tid = threadIdx.x;
  const int lane = tid & 63;
  const int wid = tid >> 6;
  const size_t row = (size_t)b * NN;

  __shared__ int cnt[NBUCK];
  __shared__ unsigned long long fsum[NBUCK];
  __shared__ int qoff[NBUCK];
  __shared__ Bucket table[NBUCK];
  __shared__ float sq[KK];
  __shared__ unsigned char elimf[HALF];
  __shared__ int wtc[8];
  __shared__ long long wtf[8];
  __shared__ double rd[8];
  __shared__ long long rf[8];
  __shared__ int rs[8];
  __shared__ unsigned long long rp[8];
  __shared__ int lastflag;

  // Prefetch survivor scores (address independent of everything else).
  const int i0 = tid * 4;
  const float4 s4 = *reinterpret_cast<const float4*>(&scores[row + n0 + i0]);

  // Per-wave inline dtype detection: 3 broadcast loads + ballots, all in
  // registers (no LDS round-trip, no wave-0 serialization).
  //   mask: float32 1.0 word = 0x3F800000; uint8-packed words exceed 1;
  //   int32 0/1 words never do.  idx: int64 < 4096 has zero odd words.
  const unsigned int mw = ((const unsigned int*)mask_v)[lane];
  const unsigned long long isF = __ballot(mw == 0x3F800000u);
  const unsigned long long gt1 = __ballot(mw > 1u);
  const unsigned int hw = ((const unsigned int*)idx_v)[2 * lane + 1];
  const unsigned long long hi = __ballot(hw != 0u);
  const int mtype = isF ? 2 : (gt1 ? 1 : 0);  // 0=int32 1=uint8 2=float32
  const int itype = hi ? 0 : 1;               // 0=int32 1=int64

  cnt[tid] = 0;  cnt[tid + BT] = 0;
  fsum[tid] = 0ull; fsum[tid + BT] = 0ull;
  ((unsigned int*)elimf)[tid] = 0u;          // 512 * 4B == HALF
  __syncthreads();  // S1

  // Query phase (tid<256): histogram valid e' into fixed-point bucket sums.
  int ki = 0; bool kvalid = false; float ep = 0.0f; int qb = 0;
  if (tid < KK) {
    if (itype) ki = (int)((const long long*)idx_v)[(size_t)b * KK + tid];
    else       ki = ((const int*)idx_v)[(size_t)b * KK + tid];
    kvalid = rmask(mask_v, mtype, row + (size_t)ki);
    ep = scores[row + (size_t)ki] + MARGIN_F;
    if (ki >= n0 && ki < n0 + HALF) elimf[ki - n0] = 1;  // same-value race ok
    if (kvalid) {
      qb = qbucket(ep);
      atomicAdd(&cnt[qb], 1);
      atomicAdd(&fsum[qb], (unsigned long long)fixv(ep));  // order-free exact
    }
  }
  // Survivor mask loads (dtype known in-register).
  bool m0, m1, m2, m3;
  {
    const size_t n = row + (size_t)(n0 + i0);
    if (mtype == 1) {
      const unsigned int w =
          *reinterpret_cast<const unsigned int*>((const unsigned char*)mask_v + n);
      m0 = (w & 0xffu) != 0;     m1 = (w & 0xff00u) != 0;
      m2 = (w & 0xff0000u) != 0; m3 = (w & 0xff000000u) != 0;
    } else if (mtype == 2) {
      const float4 w = *reinterpret_cast<const float4*>(&((const float*)mask_v)[n]);
      m0 = w.x != 0.0f; m1 = w.y != 0.0f; m2 = w.z != 0.0f; m3 = w.w != 0.0f;
    } else {
      const int4 w = *reinterpret_cast<const int4*>(&((const int*)mask_v)[n]);
      m0 = w.x != 0; m1 = w.y != 0; m2 = w.z != 0; m3 = w.w != 0;
    }
  }
  __syncthreads();  // S2

  // Suffix scan over 1024 buckets (2 per thread): counts + fixed-point sums.
  const int b0 = tid * 2;
  const int c0 = cnt[b0], c1 = cnt[b0 + 1];
  const long long f0 = (long long)fsum[b0], f1 = (long long)fsum[b0 + 1];
  int ic = c0 + c1;
  long long ifx = f0 + f1;
  for (int off = 1; off < 64; off <<= 1) {   // guarded inclusive suffix scan
    const int tc = __shfl_down(ic, off);
    const long long tf = __shfl_down(ifx, off);
    if (lane + off < 64) { ic += tc; ifx += tf; }
  }
  if (lane == 0) { wtc[wid] = ic; wtf[wid] = ifx; }
  __syncthreads();  // S3

  // Every thread: total E and strictly-above-my-waves partials in one pass.
  int wc = 0, E = 0; long long wf = 0;
#pragma unroll
  for (int w = 0; w < 8; ++w) {
    const int v = wtc[w];
    E += v;
    if (w > wid) { wc += v; wf += wtf[w]; }
  }
  const int Ac = ic - (c0 + c1) + wc;        // strictly above bucket b0+1
  const long long Af = ifx - (f0 + f1) + wf;
  const int sc1 = Ac,       sc0 = Ac + c1;
  const long long sf1 = Af, sf0 = Af + f1;
  const int q0 = E - sc0 - c0;               // prefix-below = scatter base
  const int q1 = E - sc1 - c1;
  Bucket t0; t0.sfx_f = sf0;
  t0.packed = ((unsigned int)c0 << 20) | ((unsigned int)q0 << 10) | (unsigned int)sc0;
  t0.pad = 0;
  Bucket t1; t1.sfx_f = sf1;
  t1.packed = ((unsigned int)c1 << 20) | ((unsigned int)q1 << 10) | (unsigned int)sc1;
  t1.pad = 0;
  table[b0] = t0;
  table[b0 + 1] = t1;
  qoff[b0] = 0; qoff[b0 + 1] = 0;
  __syncthreads();  // S4

  // Scatter valid e' grouped by bucket (slot order nondet -> harmless: the
  // own-bucket accumulation below is order-free fixed-point).
  if (tid < KK && kvalid) {
    const int st = (int)((table[qb].packed >> 10) & 1023u);
    sq[st + atomicAdd(&qoff[qb], 1)] = ep;
  }
  __syncthreads();  // S5

  // Survivor phase: 4 per thread, one ds_read_b128 per survivor.
  long long afix = 0; double cs = 0.0; int ns = 0;
  {
    const float sv[4] = {s4.x, s4.y, s4.z, s4.w};
    const bool mm[4] = {m0, m1, m2, m3};
#pragma unroll
    for (int e = 0; e < 4; ++e) {
      if (mm[e] && (elimf[i0 + e] == 0)) {
        const float s = sv[e];
        ++ns;
        const int q = qbucket(s);
        const Bucket bk = table[q];
        const unsigned int pk = bk.packed;
        cs += (double)(int)(pk & 1023u) * (double)s;
        afix += bk.sfx_f;
        const int st = (int)((pk >> 10) & 1023u);
        const int c = (int)(pk >> 20);
        for (int j = 0; j < c; ++j) {     // own-bucket exact scan (~0-3 elems)
          const float t = sq[st + j] - s;
          if (t > 0.0f) afix += fixv(t);
        }
      }
    }
  }

  // Block reduce (descending shuffle, lane0-valid) in fixed order.
  for (int off = 32; off > 0; off >>= 1) {
    afix += __shfl_down(afix, off);
    cs += __shfl_down(cs, off);
    ns += __shfl_down(ns, off);
  }
  if (lane == 0) { rf[wid] = afix; rd[wid] = cs; rs[wid] = ns; }
  __syncthreads();  // S6
  if (tid == 0) {
    long long F = 0; double C = 0.0; int S = 0;
#pragma unroll
    for (int w = 0; w < 8; ++w) { F += rf[w]; C += rd[w]; S += rs[w]; }
    ploss[blk] = (double)F * FIX_INV - C;
    ppairs[blk] = (unsigned int)(E * S);
    __threadfence();
    const unsigned int old = atomicAdd(counter, 1u);
    lastflag = ((old & (NBLK - 1)) == (NBLK - 1)) ? 1 : 0;  // poison-proof
  }
  __syncthreads();  // S7

  if (lastflag) {   // exactly one block per call; all partials fenced+visible
    __threadfence();
    double d = 0.0; unsigned long long p = 0ull;
    if (tid < NBLK) {
      d = __hip_atomic_load(&ploss[tid], __ATOMIC_RELAXED, __HIP_MEMORY_SCOPE_AGENT);
      p = (unsigned long long)__hip_atomic_load(&ppairs[tid], __ATOMIC_RELAXED,
                                                __HIP_MEMORY_SCOPE_AGENT);
    }
    for (int off = 32; off > 0; off >>= 1) {
      d += __shfl_down(d, off);
      p += __shfl_down(p, off);
    }
    if (lane == 0) { rd[wid] = d; rp[wid] = p; }
    __syncthreads();
    if (tid == 0) {
      double D = 0.0; unsigned long long P = 0ull;
#pragma unroll
      for (int w = 0; w < 8; ++w) { D += rd[w]; P += rp[w]; }
      out[0] = (float)(D / (P ? (double)P : 1.0));
    }
  }
}

extern "C" void kernel_launch(void* const* d_in, const int* in_sizes, int n_in,
                              void* d_out, int out_size, void* d_ws, size_t ws_size,
                              hipStream_t stream) {
  const float* scores = (const float*)d_in[0];
  const void* idx = d_in[1];
  const void* mask = d_in[2];

  char* ws = (char*)d_ws;
  unsigned int* counter = (unsigned int*)ws;
  double* ploss = (double*)(ws + 64);
  unsigned int* ppairs = (unsigned int*)(ws + 64 + NBLK * sizeof(double));
  float* out = (float*)d_out;

  pel_fused<<<NBLK, BT, 0, stream>>>(scores, idx, mask, ploss, ppairs, counter, out);
}